// Round 5
// baseline (832.819 us; speedup 1.0000x reference)
//
#include <hip/hip_runtime.h>
#include <math.h>

typedef __bf16 bf16x8 __attribute__((ext_vector_type(8)));
typedef __bf16 bf16x4 __attribute__((ext_vector_type(4)));
typedef float f32x4 __attribute__((ext_vector_type(4)));
typedef float float4v __attribute__((ext_vector_type(4)));

#define TWO_PI_F 6.28318530717958647692f
#define INV_4PI_F 0.079577471545947667884f

// packed-weight layout offsets in __bf16 elements inside d_ws
#define W1F_OFF 0
#define W1B_OFF 524288
#define W2F_OFF 1048576
#define W2B_OFF 1114112
#define W3F_OFF 1179648
#define W3B_OFF 1245184
#define W4F_OFF 1310720
#define W4B_OFF 1376256

// ---------------------------------------------------------------------------
// k_pack: coalesced LDS-transpose pack of fp32 weights into bf16 MFMA
// B-operand tile order (unchanged layout from rounds 1-4, verified passing).
// Fwd (H@W):  B[k][n] = W[k][n].  Bwd (G@W^T): B[k][n] = W[n][k].
// N=256 chunk: c = ((kc*16+ct)*4+q)*16+n holds B[kc*32+q*8+j][ct*16+n].
// W1B (N=2048): c = ((ct*8+kc)*4+q)*16+n (ct-major: one ct block = 8KB).
// ---------------------------------------------------------------------------
__global__ void k_pack(const float* __restrict__ W1, const float* __restrict__ W2,
                       const float* __restrict__ W3, const float* __restrict__ W4,
                       __bf16* __restrict__ ws) {
  __shared__ __bf16 T[32 * 264];
  int b = blockIdx.x, t = threadIdx.x;
  const float* W; long base; int kc, nb; bool bwd, w1b = false;
  if (b < 64)       { W = W1; bwd = false; base = W1F_OFF; kc = b;       nb = 0; }
  else if (b < 72)  { W = W2; bwd = false; base = W2F_OFF; kc = b - 64;  nb = 0; }
  else if (b < 80)  { W = W3; bwd = false; base = W3F_OFF; kc = b - 72;  nb = 0; }
  else if (b < 88)  { W = W4; bwd = false; base = W4F_OFF; kc = b - 80;  nb = 0; }
  else if (b < 152) { W = W1; bwd = true;  base = W1B_OFF; kc = (b - 88) & 7; nb = (b - 88) >> 3; w1b = true; }
  else if (b < 160) { W = W2; bwd = true;  base = W2B_OFF; kc = b - 152; nb = 0; }
  else if (b < 168) { W = W3; bwd = true;  base = W3B_OFF; kc = b - 160; nb = 0; }
  else              { W = W4; bwd = true;  base = W4B_OFF; kc = b - 168; nb = 0; }

  if (!bwd) {
    #pragma unroll
    for (int i = 0; i < 8; ++i) {
      int idx = t + i * 256;
      int k = idx >> 6;
      int n4 = (idx & 63) * 4;
      float4v v = *(const float4v*)(W + (size_t)(kc * 32 + k) * 256 + n4);
      #pragma unroll
      for (int j = 0; j < 4; ++j) T[k * 264 + n4 + j] = (__bf16)v[j];
    }
  } else {
    #pragma unroll
    for (int i = 0; i < 8; ++i) {
      int idx = t + i * 256;
      int n = idx >> 3;
      int k4 = (idx & 7) * 4;
      float4v v = *(const float4v*)(W + (size_t)(nb * 256 + n) * 256 + kc * 32 + k4);
      #pragma unroll
      for (int j = 0; j < 4; ++j) T[(k4 + j) * 264 + n] = (__bf16)v[j];
    }
  }
  __syncthreads();
  int ctl = t >> 4, n = t & 15;
  #pragma unroll
  for (int q = 0; q < 4; ++q) {
    bf16x8 v;
    #pragma unroll
    for (int j = 0; j < 8; ++j) v[j] = T[(q * 8 + j) * 264 + ctl * 16 + n];
    long c;
    if (w1b) c = (((long)(nb * 16 + ctl) * 8 + kc) * 4 + q) * 16 + n;
    else     c = (((long)kc * 16 + ctl) * 4 + q) * 16 + n;
    *(bf16x8*)(ws + base + c * 8) = v;
  }
}

// ---------------------------------------------------------------------------
// Biot-Savart: 2 threads/point, seg/mid precomputed once per block in LDS.
// out layout: f[N] | current[3N] | df[3N] | alpha[3N]
// ---------------------------------------------------------------------------
__global__ void k_biot(const float* __restrict__ x, const float* __restrict__ bdry,
                       float* __restrict__ out, int N, int M) {
  __shared__ float4v em[512 * 2];
  int tid = threadIdx.x;
  for (int s = tid; s < M; s += 256) {
    int sn = (s + 1 == M) ? 0 : s + 1;
    float b0 = bdry[s * 3], b1 = bdry[s * 3 + 1], b2 = bdry[s * 3 + 2];
    float c0 = bdry[sn * 3], c1 = bdry[sn * 3 + 1], c2 = bdry[sn * 3 + 2];
    float4v a = {c0 - b0, c1 - b1, c2 - b2, 0.5f * (c0 + b0)};
    float4v bv = {0.5f * (c1 + b1), 0.5f * (c2 + b2), 0.f, 0.f};
    em[s * 2] = a; em[s * 2 + 1] = bv;
  }
  __syncthreads();
  int idx = blockIdx.x * 128 + (tid >> 1);
  int half = tid & 1;
  if (idx >= N) return;
  float x0 = fminf(fmaxf(x[idx * 3 + 0], -1.f), 1.f);
  float x1 = fminf(fmaxf(x[idx * 3 + 1], -1.f), 1.f);
  float x2 = fminf(fmaxf(x[idx * 3 + 2], -1.f), 1.f);
  float a0 = 0.f, a1 = 0.f, a2 = 0.f;
  int s0i = half * (M / 2), s1i = s0i + M / 2;
  for (int s = s0i; s < s1i; ++s) {
    float4v eA = em[s * 2], eB = em[s * 2 + 1];
    float d0 = x0 - eA[3], d1 = x1 - eB[0], d2 = x2 - eB[1];
    float r2 = d0 * d0 + d1 * d1 + d2 * d2;
    float inv = rsqrtf(r2);
    float inv3 = inv * inv * inv;
    float n0 = eA[1] * d2 - eA[2] * d1;
    float n1 = eA[2] * d0 - eA[0] * d2;
    float n2 = eA[0] * d1 - eA[1] * d0;
    a0 = fmaf(n0, inv3, a0); a1 = fmaf(n1, inv3, a1); a2 = fmaf(n2, inv3, a2);
  }
  a0 += __shfl_xor(a0, 1, 64);
  a1 += __shfl_xor(a1, 1, 64);
  a2 += __shfl_xor(a2, 1, 64);
  if (!half) {
    float* alpha = out + (size_t)7 * N;
    alpha[idx * 3 + 0] = a0 * INV_4PI_F;
    alpha[idx * 3 + 1] = a1 * INV_4PI_F;
    alpha[idx * 3 + 2] = a2 * INV_4PI_F;
  }
}

// ---------------------------------------------------------------------------
// Fused MLP fwd+bwd, col-split design:
//   block = 256 thr = 4 waves, 32 rows/block; wave owns a 64-col slice of
//   ALL 32 rows. Activations live in ONE LDS buffer sA[32][264] shared by
//   all waves (A-operand). Weights are read 16B/lane straight from global
//   (L2-resident 2.9 MB) -> no LDS staging, no weight barriers.
//   softplus' (sigma) stays per-lane in regs (same lane owns same C-position
//   in fwd and bwd): 3 x 32 bf16 = 48 VGPRs -> no h-frag arrays, no spill.
// ---------------------------------------------------------------------------
__launch_bounds__(256, 3)
__global__ void k_mlp(const float* __restrict__ x, const float* __restrict__ Brff,
                      const float* __restrict__ b1, const float* __restrict__ b2,
                      const float* __restrict__ b3, const float* __restrict__ b4,
                      const float* __restrict__ W5, const float* __restrict__ b5,
                      const __bf16* __restrict__ wsw, float* __restrict__ out, int N) {
  __shared__ __attribute__((aligned(16))) __bf16 sA[32 * 264];  // 16.5 KB activations
  __shared__ float sX[96];                                      // clipped x rows
  __shared__ float sRed[384];                                   // cross-wave reductions

  const int tid  = threadIdx.x;
  const int wave = tid >> 6;
  const int lane = tid & 63;
  const int ml   = lane & 15;
  const int quad = lane >> 4;
  const int rowblk = blockIdx.x * 32;

  if (tid < 96) {
    float v = x[(size_t)rowblk * 3 + tid];
    sX[tid] = fminf(fmaxf(v, -1.f), 1.f);
  }
  __syncthreads();

  f32x4 acc[2][4];
  __bf16 sig1[32], sig2[32], sig3[32];

  auto zacc = [&]() {
    #pragma unroll
    for (int mt = 0; mt < 2; ++mt)
      #pragma unroll
      for (int nt = 0; nt < 4; ++nt) { f32x4 z = {0.f,0.f,0.f,0.f}; acc[mt][nt] = z; }
  };

  // ---- Forward layer 1: y(RFF) @ W1, K=2048, 8 chunks of K=256 through sA ----
  {
    const int yrow = tid >> 3;          // 0..31
    const int yk0  = (tid & 7) * 32;    // 0..224
    float ya0 = sX[yrow * 3], ya1 = sX[yrow * 3 + 1], ya2 = sX[yrow * 3 + 2];
    zacc();
    for (int kc8 = 0; kc8 < 8; ++kc8) {
      if (kc8) __syncthreads();         // prev GEMM chunk done reading sA
      bool isSin = (kc8 < 4);
      int cb = (kc8 & 3) * 256 + yk0;
      #pragma unroll
      for (int j4 = 0; j4 < 8; ++j4) {
        bf16x4 yv;
        #pragma unroll
        for (int j = 0; j < 4; ++j) {
          int c = cb + j4 * 4 + j;
          float t = __builtin_amdgcn_fractf(
              ya0 * Brff[c] + ya1 * Brff[1024 + c] + ya2 * Brff[2048 + c]);
          float v = isSin ? __builtin_amdgcn_sinf(t) : __builtin_amdgcn_cosf(t);
          yv[j] = (__bf16)v;
        }
        *(bf16x4*)(sA + yrow * 264 + yk0 + j4 * 4) = yv;
      }
      __syncthreads();
      #pragma unroll
      for (int kc = 0; kc < 8; ++kc) {
        bf16x8 a0 = *(const bf16x8*)(sA + ml * 264 + kc * 32 + quad * 8);
        bf16x8 a1 = *(const bf16x8*)(sA + (16 + ml) * 264 + kc * 32 + quad * 8);
        const __bf16* wp = wsw + W1F_OFF + (size_t)(kc8 * 8 + kc) * 8192 +
                           (wave * 4) * 512 + quad * 128 + ml * 8;
        #pragma unroll
        for (int nt = 0; nt < 4; ++nt) {
          bf16x8 bfr = *(const bf16x8*)(wp + nt * 512);
          acc[0][nt] = __builtin_amdgcn_mfma_f32_16x16x32_bf16(a0, bfr, acc[0][nt], 0, 0, 0);
          acc[1][nt] = __builtin_amdgcn_mfma_f32_16x16x32_bf16(a1, bfr, acc[1][nt], 0, 0, 0);
        }
      }
    }
  }

  // K=256,N=256 GEMM: A from sA (shared), B straight from global (L2)
  auto gemm = [&](long Woff) {
    zacc();
    #pragma unroll
    for (int kc = 0; kc < 8; ++kc) {
      bf16x8 a0 = *(const bf16x8*)(sA + ml * 264 + kc * 32 + quad * 8);
      bf16x8 a1 = *(const bf16x8*)(sA + (16 + ml) * 264 + kc * 32 + quad * 8);
      const __bf16* wp = wsw + Woff + kc * 8192 + (wave * 4) * 512 + quad * 128 + ml * 8;
      #pragma unroll
      for (int nt = 0; nt < 4; ++nt) {
        bf16x8 bfr = *(const bf16x8*)(wp + nt * 512);
        acc[0][nt] = __builtin_amdgcn_mfma_f32_16x16x32_bf16(a0, bfr, acc[0][nt], 0, 0, 0);
        acc[1][nt] = __builtin_amdgcn_mfma_f32_16x16x32_bf16(a1, bfr, acc[1][nt], 0, 0, 0);
      }
    }
  };

  // softplus epilogue: h -> sA, sigma -> per-lane regs
  auto epi_h = [&](const float* __restrict__ bias, __bf16* sig) {
    __syncthreads();
    float bc[4];
    #pragma unroll
    for (int nt = 0; nt < 4; ++nt) bc[nt] = bias[wave * 64 + nt * 16 + ml];
    #pragma unroll
    for (int mt = 0; mt < 2; ++mt)
      #pragma unroll
      for (int nt = 0; nt < 4; ++nt)
        #pragma unroll
        for (int r = 0; r < 4; ++r) {
          float z = acc[mt][nt][r] + bc[nt];
          float ez = __expf(-fabsf(z));
          float sp = fmaxf(z, 0.f) + __logf(1.f + ez);
          float sg = (z >= 0.f) ? 1.f / (1.f + ez) : ez / (1.f + ez);
          sig[(mt * 4 + nt) * 4 + r] = (__bf16)sg;
          sA[(mt * 16 + quad * 4 + r) * 264 + wave * 64 + nt * 16 + ml] = (__bf16)sp;
        }
    __syncthreads();
  };

  // backward gate epilogue: g = acc * sigma -> sA
  auto epi_g = [&](const __bf16* sig) {
    __syncthreads();
    #pragma unroll
    for (int mt = 0; mt < 2; ++mt)
      #pragma unroll
      for (int nt = 0; nt < 4; ++nt)
        #pragma unroll
        for (int r = 0; r < 4; ++r) {
          float g = acc[mt][nt][r] * (float)sig[(mt * 4 + nt) * 4 + r];
          sA[(mt * 16 + quad * 4 + r) * 264 + wave * 64 + nt * 16 + ml] = (__bf16)g;
        }
    __syncthreads();
  };

  // ---- Forward ----
  epi_h(b1, sig1);
  gemm(W2F_OFF); epi_h(b2, sig2);
  gemm(W3F_OFF); epi_h(b3, sig3);
  gemm(W4F_OFF);

  // ---- Layer-4 epilogue: f head + g4 = sigma(z4)*W5 -> sA ----
  {
    __syncthreads();
    float bc[4], w5c[4];
    #pragma unroll
    for (int nt = 0; nt < 4; ++nt) {
      int col = wave * 64 + nt * 16 + ml;
      bc[nt] = b4[col]; w5c[nt] = W5[col];
    }
    float fp[8] = {0.f,0.f,0.f,0.f,0.f,0.f,0.f,0.f};
    #pragma unroll
    for (int mt = 0; mt < 2; ++mt)
      #pragma unroll
      for (int nt = 0; nt < 4; ++nt)
        #pragma unroll
        for (int r = 0; r < 4; ++r) {
          float z = acc[mt][nt][r] + bc[nt];
          float ez = __expf(-fabsf(z));
          float sp = fmaxf(z, 0.f) + __logf(1.f + ez);
          float sg = (z >= 0.f) ? 1.f / (1.f + ez) : ez / (1.f + ez);
          fp[mt * 4 + r] += sp * w5c[nt];
          sA[(mt * 16 + quad * 4 + r) * 264 + wave * 64 + nt * 16 + ml] = (__bf16)(sg * w5c[nt]);
        }
    #pragma unroll
    for (int i = 0; i < 8; ++i) {
      float v = fp[i];
      #pragma unroll
      for (int m = 1; m < 16; m <<= 1) v += __shfl_xor(v, m, 64);
      fp[i] = v;
    }
    if (ml == 0) {
      #pragma unroll
      for (int mt = 0; mt < 2; ++mt)
        #pragma unroll
        for (int r = 0; r < 4; ++r)
          sRed[wave * 32 + mt * 16 + quad * 4 + r] = fp[mt * 4 + r];
    }
    __syncthreads();
    if (tid < 32)
      out[rowblk + tid] = sRed[tid] + sRed[32 + tid] + sRed[64 + tid] + sRed[96 + tid] + b5[0];
  }

  // ---- Backward through W4, W3, W2 ----
  gemm(W4B_OFF); epi_g(sig3);
  gemm(W3B_OFF); epi_g(sig2);
  gemm(W2B_OFF); epi_g(sig1);

  // ---- Backward L1: dy = g1 @ W1^T fused with dproj & dx; col pairs (c, c+1024)
  //      wave owns pair-cols [wave*256, wave*256+256). A (g1) in sA; kc<4 A-frags
  //      cached in regs to halve LDS re-reads across the 16 p-iterations. ----
  {
    bf16x8 ac0[4], ac1[4];
    #pragma unroll
    for (int kc = 0; kc < 4; ++kc) {
      ac0[kc] = *(const bf16x8*)(sA + ml * 264 + kc * 32 + quad * 8);
      ac1[kc] = *(const bf16x8*)(sA + (16 + ml) * 264 + kc * 32 + quad * 8);
    }
    float xr[8][3];
    #pragma unroll
    for (int mt = 0; mt < 2; ++mt)
      #pragma unroll
      for (int r = 0; r < 4; ++r) {
        int row = mt * 16 + quad * 4 + r;
        xr[mt * 4 + r][0] = sX[row * 3];
        xr[mt * 4 + r][1] = sX[row * 3 + 1];
        xr[mt * 4 + r][2] = sX[row * 3 + 2];
      }
    float dxa[8][3];
    #pragma unroll
    for (int i = 0; i < 8; ++i) { dxa[i][0] = 0.f; dxa[i][1] = 0.f; dxa[i][2] = 0.f; }

    for (int p = 0; p < 16; ++p) {
      const __bf16* wpA = wsw + W1B_OFF + (size_t)(wave * 16 + p) * 4096 + quad * 128 + ml * 8;
      const __bf16* wpB = wpA + (size_t)64 * 4096;
      f32x4 aA0 = {0.f,0.f,0.f,0.f}, aA1 = {0.f,0.f,0.f,0.f};
      f32x4 aB0 = {0.f,0.f,0.f,0.f}, aB1 = {0.f,0.f,0.f,0.f};
      #pragma unroll
      for (int kc = 0; kc < 8; ++kc) {
        bf16x8 a0 = (kc < 4) ? ac0[kc]
                  : *(const bf16x8*)(sA + ml * 264 + kc * 32 + quad * 8);
        bf16x8 a1 = (kc < 4) ? ac1[kc]
                  : *(const bf16x8*)(sA + (16 + ml) * 264 + kc * 32 + quad * 8);
        bf16x8 bA = *(const bf16x8*)(wpA + kc * 512);
        bf16x8 bB = *(const bf16x8*)(wpB + kc * 512);
        aA0 = __builtin_amdgcn_mfma_f32_16x16x32_bf16(a0, bA, aA0, 0, 0, 0);
        aA1 = __builtin_amdgcn_mfma_f32_16x16x32_bf16(a1, bA, aA1, 0, 0, 0);
        aB0 = __builtin_amdgcn_mfma_f32_16x16x32_bf16(a0, bB, aB0, 0, 0, 0);
        aB1 = __builtin_amdgcn_mfma_f32_16x16x32_bf16(a1, bB, aB1, 0, 0, 0);
      }
      int c = wave * 256 + p * 16 + ml;
      float B0 = Brff[c], B1 = Brff[1024 + c], B2 = Brff[2048 + c];
      #pragma unroll
      for (int mt = 0; mt < 2; ++mt)
        #pragma unroll
        for (int r = 0; r < 4; ++r) {
          float dyA = mt ? aA1[r] : aA0[r];
          float dyB = mt ? aB1[r] : aB0[r];
          float t = __builtin_amdgcn_fractf(
              xr[mt * 4 + r][0] * B0 + xr[mt * 4 + r][1] * B1 + xr[mt * 4 + r][2] * B2);
          float sn = __builtin_amdgcn_sinf(t);
          float cs = __builtin_amdgcn_cosf(t);
          float dp = dyA * cs - dyB * sn;
          dxa[mt * 4 + r][0] = fmaf(dp, B0, dxa[mt * 4 + r][0]);
          dxa[mt * 4 + r][1] = fmaf(dp, B1, dxa[mt * 4 + r][1]);
          dxa[mt * 4 + r][2] = fmaf(dp, B2, dxa[mt * 4 + r][2]);
        }
    }

    // reduce dx over ml lanes, then across waves via LDS
    #pragma unroll
    for (int i = 0; i < 8; ++i)
      #pragma unroll
      for (int k = 0; k < 3; ++k) {
        float v = dxa[i][k];
        #pragma unroll
        for (int m = 1; m < 16; m <<= 1) v += __shfl_xor(v, m, 64);
        dxa[i][k] = v;
      }
    if (ml == 0) {
      #pragma unroll
      for (int mt = 0; mt < 2; ++mt)
        #pragma unroll
        for (int r = 0; r < 4; ++r) {
          int row = mt * 16 + quad * 4 + r;
          sRed[wave * 96 + row * 3 + 0] = dxa[mt * 4 + r][0];
          sRed[wave * 96 + row * 3 + 1] = dxa[mt * 4 + r][1];
          sRed[wave * 96 + row * 3 + 2] = dxa[mt * 4 + r][2];
        }
    }
    __syncthreads();
    if (tid < 96) {
      float v = (sRed[tid] + sRed[96 + tid] + sRed[192 + tid] + sRed[288 + tid]) * TWO_PI_F;
      size_t gi = (size_t)rowblk * 3 + tid;
      out[(size_t)4 * N + gi] = v;                              // df
      out[(size_t)N + gi] = v + out[(size_t)7 * N + gi];        // current = df + alpha
    }
  }
}

extern "C" void kernel_launch(void* const* d_in, const int* in_sizes, int n_in,
                              void* d_out, int out_size, void* d_ws, size_t ws_size,
                              hipStream_t stream) {
  const float* x    = (const float*)d_in[0];
  const float* bdry = (const float*)d_in[1];
  const float* Brff = (const float*)d_in[2];
  const float* W1   = (const float*)d_in[3];
  const float* b1   = (const float*)d_in[4];
  const float* W2   = (const float*)d_in[5];
  const float* b2   = (const float*)d_in[6];
  const float* W3   = (const float*)d_in[7];
  const float* b3   = (const float*)d_in[8];
  const float* W4   = (const float*)d_in[9];
  const float* b4   = (const float*)d_in[10];
  const float* W5   = (const float*)d_in[11];
  const float* b5   = (const float*)d_in[12];
  float* out = (float*)d_out;
  __bf16* ws = (__bf16*)d_ws;
  int N = in_sizes[0] / 3;   // 65536
  int M = in_sizes[1] / 3;   // 512

  k_pack<<<176, 256, 0, stream>>>(W1, W2, W3, W4, ws);
  k_biot<<<(N + 127) / 128, 256, 0, stream>>>(x, bdry, out, N, M);
  k_mlp<<<N / 32, 256, 0, stream>>>(x, Brff, b1, b2, b3, b4, W5, b5, ws, out, N);
}